// Round 7
// baseline (352.065 us; speedup 1.0000x reference)
//
#include <hip/hip_runtime.h>

// TreeLSTM cell: one bf16-MFMA GEMM [131072,512]x[512,1024] + gated epilogue.
// v8: occupancy lever. Wave tile 32 rows x (4seg x 32 hcol) -> acc f32x16[4] = 64 AGPR
// (v7 had 128 -> 2 waves/SIMD in ALL prior variants; the schedule-independent 21%
// MfmaUtil ceiling). ~150 total regs + __launch_bounds__(256,3) -> 3 waves/SIMD,
// 3 independent blocks/CU. Structure otherwise v7: A staged via swizzled
// global_load_lds dbuf (one vmcnt(8)+barrier per kt), B direct global->reg in
// fragment order (L2-resident 1MB), i,o,u,f lane-local epilogue.

typedef unsigned short u16;
typedef unsigned int u32;
typedef __bf16 bf16x8 __attribute__((ext_vector_type(8)));
typedef float f32x16 __attribute__((ext_vector_type(16)));
typedef u16 u16x4 __attribute__((ext_vector_type(4)));
typedef u16 u16x8 __attribute__((ext_vector_type(8)));

#define NTOT 131072
#define NHOFF ((size_t)131072 * 256)
#define AS1 __attribute__((address_space(1)))
#define AS3 __attribute__((address_space(3)))

__device__ __forceinline__ u16 f2bf(float f) {
  u32 u = __float_as_uint(f);
  return (u16)((u + 0x7FFFu + ((u >> 16) & 1u)) >> 16);  // RNE
}

// ---- B in fragment order (verified r3/v7): [g(4)][kt(8)][ks(4)][hi(2)][np(256)][8 bf16]
// np = nf*64 + wn*32 + lr  ->  pre-col j = nf*256 + g*64 + wn*32 + lr  (seg nf).
__global__ void prep_w_frag(const float* __restrict__ Wiou, const float* __restrict__ Uiou,
                            const float* __restrict__ Wf, const float* __restrict__ Uf,
                            u16* __restrict__ BpackF) {
  int c = blockIdx.x * 256 + threadIdx.x;  // 65536 chunks of 8 k-elems
  int np = c & 255;
  int r = c >> 8;
  int hi = r & 1; r >>= 1;
  int ks = r & 3; r >>= 2;
  int kt = r & 7; r >>= 3;
  int g  = r & 3;
  int j = (np >> 6) * 256 + g * 64 + (np & 63);
  int k0 = kt * 64 + ks * 16 + hi * 8;
  const float* src;
  if (j < 768) src = (k0 < 256) ? (Wiou + (size_t)j * 256 + k0) : (Uiou + (size_t)j * 256 + (k0 - 256));
  else { int jj = j - 768; src = (k0 < 256) ? (Wf + (size_t)jj * 256 + k0) : (Uf + (size_t)jj * 256 + (k0 - 256)); }
  float4 f0 = *(const float4*)(src);
  float4 f1 = *(const float4*)(src + 4);
  u16x8 v;
  v[0] = f2bf(f0.x); v[1] = f2bf(f0.y); v[2] = f2bf(f0.z); v[3] = f2bf(f0.w);
  v[4] = f2bf(f1.x); v[5] = f2bf(f1.y); v[6] = f2bf(f1.z); v[7] = f2bf(f1.w);
  *(u16x8*)(BpackF + (size_t)c * 8) = v;
}

// ---- legacy B layout (fallback path only) ----
__global__ void prep_w_legacy(const float* __restrict__ Wiou, const float* __restrict__ Uiou,
                              const float* __restrict__ Wf, const float* __restrict__ Uf,
                              u16* __restrict__ Bpack) {
  int cid = blockIdx.x * 256 + threadIdx.x;
  int j = cid >> 6;
  int kc = cid & 63;
  int k = kc * 8;
  int kt = kc >> 3, k8 = kc & 7;
  int s = j >> 8, g = (j >> 6) & 3, e = j & 63;
  int c = s * 64 + e;
  const float* src;
  if (j < 768) src = (k < 256) ? (Wiou + j * 256 + k) : (Uiou + j * 256 + (k - 256));
  else { int jj = j - 768; src = (k < 256) ? (Wf + jj * 256 + k) : (Uf + jj * 256 + (k - 256)); }
  float4 f0 = *(const float4*)(src);
  float4 f1 = *(const float4*)(src + 4);
  u16x8 v;
  v[0] = f2bf(f0.x); v[1] = f2bf(f0.y); v[2] = f2bf(f0.z); v[3] = f2bf(f0.w);
  v[4] = f2bf(f1.x); v[5] = f2bf(f1.y); v[6] = f2bf(f1.z); v[7] = f2bf(f1.w);
  int slot = (g * 8 + kt) * 2048 + ((c * 8 + k8) ^ (c & 7));
  *(u16x8*)(Bpack + slot * 8) = v;
}

__global__ void prep_bias(const float* __restrict__ biou, const float* __restrict__ wfb,
                          const float* __restrict__ ufb, const float* __restrict__ bfv,
                          float* __restrict__ Bias) {
  int j = blockIdx.x * 256 + threadIdx.x;  // 1024 exact
  Bias[j] = (j < 768) ? biou[j] : (wfb[j - 768] + ufb[j - 768] + bfv[j - 768]);
}

// Apack[n] = [ x[n] (512B bf16) | child_h[idx[n]] (512B bf16) ], row-major.
__global__ void prep_apack(const float* __restrict__ x, const float* __restrict__ ch,
                           const int* __restrict__ cidx, u16* __restrict__ Apack) {
  int e = blockIdx.x * 256 + threadIdx.x;  // 131072 rows x 64 chunks of 8
  int n = e >> 6, c = e & 63;
  const float* src = (c < 32) ? (x + (size_t)n * 256 + c * 8)
                              : (ch + (size_t)cidx[n] * 256 + (c - 32) * 8);
  float4 f0 = *(const float4*)src;
  float4 f1 = *(const float4*)(src + 4);
  u16x8 v;
  v[0] = f2bf(f0.x); v[1] = f2bf(f0.y); v[2] = f2bf(f0.z); v[3] = f2bf(f0.w);
  v[4] = f2bf(f1.x); v[5] = f2bf(f1.y); v[6] = f2bf(f1.z); v[7] = f2bf(f1.w);
  *(u16x8*)(Apack + (size_t)n * 512 + c * 8) = v;
}

// -------------------- v8 main: small wave tile, 3 waves/SIMD --------------------
__global__ __launch_bounds__(256, 3)
void treelstm_main_v8(const u16* __restrict__ Apack, const u16* __restrict__ BpackF,
                      const float* __restrict__ Bias, const float* __restrict__ child_c,
                      const int* __restrict__ cidx, float* __restrict__ out) {
  __shared__ __align__(16) u16 ldsA[2 * 4096];   // 2 x 8KB A tiles (64 rows x 64 k)
  __shared__ int lds_cidx[64];
  char* ldsByte = (char*)ldsA;

  const int tid = threadIdx.x;
  // XCD-chunked bijective swizzle (8192 % 8 == 0); g-inner: 4 sibling g-blocks of one
  // A row-tile adjacent on the same XCD (A + child_c L2 reuse).
  const int orig = blockIdx.x;
  const int bid = (orig & 7) * 1024 + (orig >> 3);
  const int g = bid & 3;
  const int n0 = (bid >> 2) * 64;

  if (tid < 64) lds_cidx[tid] = cidx[n0 + tid];   // visible after iter-0 barrier

  const int lane = tid & 63, w = tid >> 6;
  const int wm = w >> 1, wn = w & 1;   // wave tile: 32 rows x (4 segs x 32 hcols)
  const int lr = lane & 31, hi = lane >> 5;

  // A staging source: per-lane, inverse-swizzled (rule #21); LDS dest linear.
  // pass q covers rows q*32..q*32+31; row&7 == (tid>>3)&7 for both passes.
  const u16* aSrc = Apack + (size_t)(n0 + (tid >> 3)) * 512
                    + (((tid & 7) ^ ((tid >> 3) & 7)) << 3);
  // B fragment base: lanes 0-31 one contiguous 512B block, lanes 32-63 the hi=1
  // block 4KB away -> fully coalesced dwordx4 (L2/L1-resident 1MB).
  const u16* bP = BpackF + (size_t)g * 131072 + (size_t)hi * 2048 + (size_t)(wn * 32 + lr) * 8;

  const int arowB = (wm * 32 + lr) * 128;       // A byte row within buffer
  int aoff[4];
  #pragma unroll
  for (int ks = 0; ks < 4; ++ks) aoff[ks] = (ks * 32 + hi * 16) ^ ((lr & 7) << 4);

  f32x16 acc[4] = {};   // [seg] -- 64 AGPR

  #define STAGE_A(T)                                                            \
    { _Pragma("unroll") for (int q = 0; q < 2; ++q)                             \
        __builtin_amdgcn_global_load_lds(                                       \
            (const AS1 void*)(aSrc + (T) * 64 + q * 16384),                     \
            (AS3 void*)(ldsByte + ((T) & 1) * 8192 + q * 4096 + w * 1024),      \
            16, 0, 0); }

  STAGE_A(0);

  #pragma unroll
  for (int t = 0; t < 8; ++t) {
    // ---- B half0 (ks=0,1): 8 coalesced global loads straight to VGPRs ----
    bf16x8 b01[4][2];
    #pragma unroll
    for (int nf = 0; nf < 4; ++nf)
      #pragma unroll
      for (int kk = 0; kk < 2; ++kk)
        b01[nf][kk] = *(const bf16x8*)(bP + (size_t)t * 16384 + kk * 4096 + nf * 512);
    // ---- A(t) ready gate: own outstanding = [STAGE_A(t) 2, b01 8] -> vmcnt(8) ----
    __builtin_amdgcn_sched_barrier(0);
    asm volatile("s_waitcnt vmcnt(8) lgkmcnt(0)\n\ts_barrier" ::: "memory");
    __builtin_amdgcn_sched_barrier(0);
    // ---- A fragments from LDS (swizzled); compiler inserts lgkm + b01 vmcnt waits ----
    const char* bufA = ldsByte + (t & 1) * 8192;
    bf16x8 af[4];
    #pragma unroll
    for (int ks = 0; ks < 4; ++ks)
      af[ks] = *(const bf16x8*)(bufA + arowB + aoff[ks]);
    // ---- MFMA half0 ----
    __builtin_amdgcn_s_setprio(1);
    #pragma unroll
    for (int kk = 0; kk < 2; ++kk)
      #pragma unroll
      for (int nf = 0; nf < 4; ++nf)
        acc[nf] = __builtin_amdgcn_mfma_f32_32x32x16_bf16(af[kk], b01[nf][kk],
                                                          acc[nf], 0, 0, 0);
    __builtin_amdgcn_s_setprio(0);
    // ---- B half1 (ks=2,3), then next A prefetch (newer than b23 so the compiler's
    // wait-for-b23 before MFMA half1 leaves STAGE_A(t+1) in flight) ----
    bf16x8 b23[4][2];
    #pragma unroll
    for (int nf = 0; nf < 4; ++nf)
      #pragma unroll
      for (int kk = 0; kk < 2; ++kk)
        b23[nf][kk] = *(const bf16x8*)(bP + (size_t)t * 16384 + (kk + 2) * 4096 + nf * 512);
    if (t < 7) STAGE_A(t + 1);
    // ---- MFMA half1 ----
    __builtin_amdgcn_s_setprio(1);
    #pragma unroll
    for (int kk = 0; kk < 2; ++kk)
      #pragma unroll
      for (int nf = 0; nf < 4; ++nf)
        acc[nf] = __builtin_amdgcn_mfma_f32_32x32x16_bf16(af[kk + 2], b23[nf][kk],
                                                          acc[nf], 0, 0, 0);
    __builtin_amdgcn_s_setprio(0);
  }
  #undef STAGE_A

  // ---- epilogue: i,o,u,f are acc[0..3][reg] in the SAME lane ----
  const int hcol = g * 64 + wn * 32 + lr;
  float b4[4];
  #pragma unroll
  for (int nf = 0; nf < 4; ++nf) b4[nf] = Bias[nf * 256 + hcol];
  #pragma unroll
  for (int reg = 0; reg < 16; ++reg) {
    int rowb = wm * 32 + (reg & 3) + 8 * (reg >> 2) + 4 * hi;  // C/D map (m74/m101)
    size_t n = (size_t)(n0 + rowb);
    float i_ = acc[0][reg] + b4[0];
    float o_ = acc[1][reg] + b4[1];
    float u_ = acc[2][reg] + b4[2];
    float fp = acc[3][reg] + b4[3];
    float ccv = child_c[(size_t)lds_cidx[rowb] * 256 + hcol];
    float sigi = 1.f / (1.f + __expf(-i_));
    float sigo = 1.f / (1.f + __expf(-o_));
    float sigf = 1.f / (1.f + __expf(-fp));
    float tu = 2.f / (1.f + __expf(-2.f * u_)) - 1.f;
    float c = sigi * tu + sigf * ccv;
    float tc = 2.f / (1.f + __expf(-2.f * c)) - 1.f;
    out[n * 256 + hcol] = sigo * tc;
    out[NHOFF + n * 256 + hcol] = c;
  }
}

// ---------- fallback main (round-1 proven path, used if ws too small) ----------
__global__ __launch_bounds__(256, 2)
void treelstm_main_f32(const float* __restrict__ x, const float* __restrict__ child_h,
                       const float* __restrict__ child_c, const int* __restrict__ cidx,
                       const u16* __restrict__ Bpack, const float* __restrict__ Bias,
                       float* __restrict__ out) {
  __shared__ __align__(16) u16 ldsA[128 * 64];
  __shared__ __align__(16) u16 ldsB[256 * 64];
  __shared__ int lds_cidx[128];

  const int tid = threadIdx.x;
  const int n0 = blockIdx.x * 128;
  const int g = blockIdx.y;

  if (tid < 128) lds_cidx[tid] = cidx[n0 + tid];

  const int lane = tid & 63, w = tid >> 6;
  const int wm = w >> 1, wn = w & 1;
  const int lr = lane & 31, hi = lane >> 5;

  f32x16 acc[2][4] = {};

  const char* ldsAb = (const char*)ldsA;
  const char* ldsBb = (const char*)ldsB;
  int arow[2];
  #pragma unroll
  for (int mi = 0; mi < 2; mi++) arow[mi] = (wm * 64 + mi * 32 + lr) * 128;
  const int aswz = (lr & 7) << 4;
  int brow[4];
  #pragma unroll
  for (int s = 0; s < 4; s++) brow[s] = (s * 64 + wn * 32 + lr) * 128;
  const int bswz = (lr & 7) << 4;

  for (int kt = 0; kt < 8; ++kt) {
    #pragma unroll
    for (int q = 0; q < 8; ++q) {
      int v = q * 256 + tid;
      int r = v >> 4;
      int kq = (v & 15) * 4;
      const float* src = (kt < 4) ? (x + (size_t)(n0 + r) * 256 + kt * 64 + kq)
                                  : (child_h + (size_t)lds_cidx[r] * 256 + (kt - 4) * 64 + kq);
      float4 d = *(const float4*)src;
      u16x4 b;
      b[0] = f2bf(d.x); b[1] = f2bf(d.y); b[2] = f2bf(d.z); b[3] = f2bf(d.w);
      int addr = (r * 128 + kq * 2) ^ ((r & 7) << 4);
      *(u16x4*)((char*)ldsA + addr) = b;
    }
    const u16* bsrc = Bpack + (g * 8 + kt) * 16384;
    #pragma unroll
    for (int q = 0; q < 8; ++q) {
      int m = q * 256 + tid;
      *(u16x8*)((char*)ldsB + m * 16) = *(const u16x8*)(bsrc + m * 8);
    }
    __syncthreads();
    #pragma unroll
    for (int ks = 0; ks < 4; ++ks) {
      int kb = ks * 32 + hi * 16;
      bf16x8 af[2], bfr[4];
      #pragma unroll
      for (int mi = 0; mi < 2; mi++)
        af[mi] = *(const bf16x8*)(ldsAb + ((arow[mi] + kb) ^ aswz));
      #pragma unroll
      for (int s = 0; s < 4; s++)
        bfr[s] = *(const bf16x8*)(ldsBb + ((brow[s] + kb) ^ bswz));
      #pragma unroll
      for (int mi = 0; mi < 2; mi++)
        #pragma unroll
        for (int s = 0; s < 4; s++)
          acc[mi][s] = __builtin_amdgcn_mfma_f32_32x32x16_bf16(af[mi], bfr[s], acc[mi][s], 0, 0, 0);
    }
    __syncthreads();
  }

  const int tcol = g * 64 + wn * 32 + lr;
  const float bi = Bias[tcol], bo = Bias[256 + tcol], bu = Bias[512 + tcol], bfg = Bias[768 + tcol];
  #pragma unroll
  for (int mi = 0; mi < 2; mi++) {
    #pragma unroll
    for (int reg = 0; reg < 16; ++reg) {
      int row = wm * 64 + mi * 32 + (reg & 3) + 8 * (reg >> 2) + 4 * hi;
      int n = n0 + row;
      float i_ = acc[mi][0][reg] + bi;
      float o_ = acc[mi][1][reg] + bo;
      float u_ = acc[mi][2][reg] + bu;
      float fp = acc[mi][3][reg] + bfg;
      float ccv = child_c[(size_t)lds_cidx[row] * 256 + tcol];
      float sigi = 1.f / (1.f + __expf(-i_));
      float sigo = 1.f / (1.f + __expf(-o_));
      float sigf = 1.f / (1.f + __expf(-fp));
      float tu = 2.f / (1.f + __expf(-2.f * u_)) - 1.f;
      float c = sigi * tu + sigf * ccv;
      float tc = 2.f / (1.f + __expf(-2.f * c)) - 1.f;
      out[(size_t)n * 256 + tcol] = sigo * tc;
      out[NHOFF + (size_t)n * 256 + tcol] = c;
    }
  }
}

extern "C" void kernel_launch(void* const* d_in, const int* in_sizes, int n_in,
                              void* d_out, int out_size, void* d_ws, size_t ws_size,
                              hipStream_t stream) {
  const float* x    = (const float*)d_in[0];
  const float* ch   = (const float*)d_in[1];
  const float* cc   = (const float*)d_in[2];
  const int*   ci   = (const int*)d_in[3];
  const float* Wiou = (const float*)d_in[4];
  const float* Uiou = (const float*)d_in[5];
  const float* biou = (const float*)d_in[6];
  const float* Wf   = (const float*)d_in[7];
  const float* Wfb  = (const float*)d_in[8];
  const float* Uf   = (const float*)d_in[9];
  const float* Ufb  = (const float*)d_in[10];
  const float* bfv  = (const float*)d_in[11];

  u16* Bpack = (u16*)d_ws;                              // 1 MB bf16 packed weights
  float* Bias = (float*)((char*)d_ws + (1 << 20));      // 4 KB combined bias
  u16* Apack = (u16*)((char*)d_ws + (2 << 20));         // 134.2 MB packed [x|hc] bf16

  const size_t need = (size_t)(2 << 20) + (size_t)NTOT * 512 * sizeof(u16);

  prep_bias<<<4, 256, 0, stream>>>(biou, Wfb, Ufb, bfv, Bias);

  if (ws_size >= need) {
    prep_w_frag<<<256, 256, 0, stream>>>(Wiou, Uiou, Wf, Uf, Bpack);
    prep_apack<<<32768, 256, 0, stream>>>(x, ch, ci, Apack);
    treelstm_main_v8<<<8192, 256, 0, stream>>>(Apack, Bpack, Bias, cc, ci, (float*)d_out);
  } else {
    prep_w_legacy<<<256, 256, 0, stream>>>(Wiou, Uiou, Wf, Uf, Bpack);
    dim3 grid(1024, 4);
    treelstm_main_f32<<<grid, 256, 0, stream>>>(x, ch, cc, ci, Bpack, Bias, (float*)d_out);
  }
}

// Round 9
// 334.418 us; speedup vs baseline: 1.0528x; 1.0528x over previous
//
#include <hip/hip_runtime.h>

// TreeLSTM cell: one bf16-MFMA GEMM [131072,512]x[512,1024] + gated epilogue.
// v10 = v9 (m201 8-phase 256^2 template) + two memory-ordering fixes:
//  (1) every s_barrier is followed by sched_barrier(0) -- raw s_barrier is not a
//      compiler fence; without it hipcc hoists next-phase ds_reads above the
//      barrier, reading LDS before OTHER waves' global_load_lds landed.
//  (2) same-parity stages issue only after the final barrier following the last
//      phase that samples that buffer (B: p2+, A: p3+); opposite-parity anywhere.
// Block 256 rows x 256 pcols (pcol -> j = fc*256 + g*64 + wn*16 + e16, fc = gate
// seg -> i,o,u,f lane-local). 512 thr / 8 waves (2Mx4N), per-wave 128x64,
// mfma 16x16x32. vmcnt(6) once per K-tile (hand-enumerated), 128 KB LDS dbuf.

typedef unsigned short u16;
typedef unsigned int u32;
typedef __bf16 bf16x8 __attribute__((ext_vector_type(8)));
typedef float f32x4 __attribute__((ext_vector_type(4)));
typedef float f32x16 __attribute__((ext_vector_type(16)));
typedef u16 u16x4 __attribute__((ext_vector_type(4)));
typedef u16 u16x8 __attribute__((ext_vector_type(8)));

#define NTOT 131072
#define NHOFF ((size_t)131072 * 256)
#define AS1 __attribute__((address_space(1)))
#define AS3 __attribute__((address_space(3)))

__device__ __forceinline__ u16 f2bf(float f) {
  u32 u = __float_as_uint(f);
  return (u16)((u + 0x7FFFu + ((u >> 16) & 1u)) >> 16);  // RNE
}

// ---- v9 B image: [g][kt][pcol(256)][c16(8)] 16B slots ----
// slot c16 of row pcol holds chunk c16 ^ (pcol&7); pcol = wn*64 + fc*16 + e16
// maps to pre-col j = fc*256 + g*64 + wn*16 + e16  (fc = gate segment).
__global__ void prep_w_v9(const float* __restrict__ Wiou, const float* __restrict__ Uiou,
                          const float* __restrict__ Wf, const float* __restrict__ Uf,
                          u16* __restrict__ Bpack) {
  int cid = blockIdx.x * 256 + threadIdx.x;   // 65536 slots of 16B
  int slot = cid & 2047;
  int kt = (cid >> 11) & 7;
  int g = cid >> 14;
  int pcol = slot >> 3, c16 = slot & 7;
  int wn = pcol >> 6, fc = (pcol >> 4) & 3, e16 = pcol & 15;
  int j = fc * 256 + g * 64 + wn * 16 + e16;
  int k0 = kt * 64 + (c16 ^ (pcol & 7)) * 8;
  const float* src;
  if (j < 768) src = (k0 < 256) ? (Wiou + (size_t)j * 256 + k0) : (Uiou + (size_t)j * 256 + (k0 - 256));
  else { int jj = j - 768; src = (k0 < 256) ? (Wf + (size_t)jj * 256 + k0) : (Uf + (size_t)jj * 256 + (k0 - 256)); }
  float4 f0 = *(const float4*)(src);
  float4 f1 = *(const float4*)(src + 4);
  u16x8 v;
  v[0] = f2bf(f0.x); v[1] = f2bf(f0.y); v[2] = f2bf(f0.z); v[3] = f2bf(f0.w);
  v[4] = f2bf(f1.x); v[5] = f2bf(f1.y); v[6] = f2bf(f1.z); v[7] = f2bf(f1.w);
  *(u16x8*)(Bpack + (size_t)cid * 8) = v;
}

// ---- legacy B layout (fallback path only) ----
__global__ void prep_w_legacy(const float* __restrict__ Wiou, const float* __restrict__ Uiou,
                              const float* __restrict__ Wf, const float* __restrict__ Uf,
                              u16* __restrict__ Bpack) {
  int cid = blockIdx.x * 256 + threadIdx.x;
  int j = cid >> 6;
  int kc = cid & 63;
  int k = kc * 8;
  int kt = kc >> 3, k8 = kc & 7;
  int s = j >> 8, g = (j >> 6) & 3, e = j & 63;
  int c = s * 64 + e;
  const float* src;
  if (j < 768) src = (k < 256) ? (Wiou + j * 256 + k) : (Uiou + j * 256 + (k - 256));
  else { int jj = j - 768; src = (k < 256) ? (Wf + jj * 256 + k) : (Uf + jj * 256 + (k - 256)); }
  float4 f0 = *(const float4*)(src);
  float4 f1 = *(const float4*)(src + 4);
  u16x8 v;
  v[0] = f2bf(f0.x); v[1] = f2bf(f0.y); v[2] = f2bf(f0.z); v[3] = f2bf(f0.w);
  v[4] = f2bf(f1.x); v[5] = f2bf(f1.y); v[6] = f2bf(f1.z); v[7] = f2bf(f1.w);
  int slot = (g * 8 + kt) * 2048 + ((c * 8 + k8) ^ (c & 7));
  *(u16x8*)(Bpack + slot * 8) = v;
}

__global__ void prep_bias(const float* __restrict__ biou, const float* __restrict__ wfb,
                          const float* __restrict__ ufb, const float* __restrict__ bfv,
                          float* __restrict__ Bias) {
  int j = blockIdx.x * 256 + threadIdx.x;  // 1024 exact
  Bias[j] = (j < 768) ? biou[j] : (wfb[j - 768] + ufb[j - 768] + bfv[j - 768]);
}

// Apack[n] = [ x[n] (512B bf16) | child_h[idx[n]] (512B bf16) ], row-major.
__global__ void prep_apack(const float* __restrict__ x, const float* __restrict__ ch,
                           const int* __restrict__ cidx, u16* __restrict__ Apack) {
  int e = blockIdx.x * 256 + threadIdx.x;  // 131072 rows x 64 chunks of 8
  int n = e >> 6, c = e & 63;
  const float* src = (c < 32) ? (x + (size_t)n * 256 + c * 8)
                              : (ch + (size_t)cidx[n] * 256 + (c - 32) * 8);
  float4 f0 = *(const float4*)src;
  float4 f1 = *(const float4*)(src + 4);
  u16x8 v;
  v[0] = f2bf(f0.x); v[1] = f2bf(f0.y); v[2] = f2bf(f0.z); v[3] = f2bf(f0.w);
  v[4] = f2bf(f1.x); v[5] = f2bf(f1.y); v[6] = f2bf(f1.z); v[7] = f2bf(f1.w);
  *(u16x8*)(Apack + (size_t)n * 512 + c * 8) = v;
}

// -------------------- v10 main: m201 8-phase template, fenced --------------------
__global__ __launch_bounds__(512, 2)
void treelstm_v10(const u16* __restrict__ Apack, const u16* __restrict__ Bpack,
                  const float* __restrict__ Bias, const float* __restrict__ child_c,
                  const int* __restrict__ cidx, float* __restrict__ out) {
  // LDS bytes: Abuf0 [0,32K) Abuf1 [32K,64K) Bbuf0 [64K,96K) Bbuf1 [96K,128K)
  __shared__ __align__(16) char lds[131072];
  __shared__ int lds_cidx[256];

  const int tid = threadIdx.x;
  // XCD-chunked bijective swizzle (2048 % 8 == 0), g-inner for A-tile L2 reuse.
  const int orig = blockIdx.x;
  const int bid = (orig & 7) * 256 + (orig >> 3);
  const int g = bid & 3;
  const int n0 = (bid >> 2) * 256;
  if (tid < 256) lds_cidx[tid] = cidx[n0 + tid];   // covered by prologue barrier

  const int l = tid & 63, w = tid >> 6;
  const int wm = w >> 2, wn = w & 3;   // per-wave: 128 rows x 64 pcols
  const int l15 = l & 15, lhi = l >> 4;

  // A staging src: per-lane, inverse-swizzled (rule #21); LDS dest linear.
  const char* aSrc = (const char*)Apack + (size_t)(n0 + (tid >> 3)) * 1024
                     + (((tid & 7) ^ ((tid >> 3) & 7)) << 4);
  // B staging src: pre-swizzled image, fully linear copy.
  const char* bSrc = (const char*)Bpack + (size_t)g * 262144 + (size_t)tid * 16;

  // ds_read bases (XOR swizzle on the read side)
  const int aBase = wm * 16384 + l15 * 128;
  const int bBase = 65536 + wn * 8192 + l15 * 128;
  int koff[2];
  koff[0] = (lhi * 16) ^ ((l & 7) << 4);
  koff[1] = (64 + lhi * 16) ^ ((l & 7) << 4);

  f32x4 acc[8][4] = {};           // [fm][fc=seg], 128 regs
  bf16x8 a[4][2], b0[2][2], b1[2][2];

  #define ST_A(KT, H)                                                              \
    { __builtin_amdgcn_global_load_lds(                                            \
          (const AS1 void*)(aSrc + (KT) * 128 + ((H) * 128 + 0) * 1024),           \
          (AS3 void*)(lds + ((KT) & 1) * 32768 + (H) * 16384 + tid * 16), 16, 0, 0); \
      __builtin_amdgcn_global_load_lds(                                            \
          (const AS1 void*)(aSrc + (KT) * 128 + ((H) * 128 + 64) * 1024),          \
          (AS3 void*)(lds + ((KT) & 1) * 32768 + (H) * 16384 + 8192 + tid * 16), 16, 0, 0); }
  #define ST_B(KT, H)                                                              \
    { __builtin_amdgcn_global_load_lds(                                            \
          (const AS1 void*)(bSrc + (KT) * 32768 + (H) * 16384),                    \
          (AS3 void*)(lds + 65536 + ((KT) & 1) * 32768 + (H) * 16384 + tid * 16), 16, 0, 0); \
      __builtin_amdgcn_global_load_lds(                                            \
          (const AS1 void*)(bSrc + (KT) * 32768 + (H) * 16384 + 8192),             \
          (AS3 void*)(lds + 65536 + ((KT) & 1) * 32768 + (H) * 16384 + 8192 + tid * 16), 16, 0, 0); }

  #define RD_A(PAR, FMB)                                                           \
    { _Pragma("unroll") for (int i = 0; i < 4; ++i)                                \
      _Pragma("unroll") for (int kh = 0; kh < 2; ++kh)                             \
        a[i][kh] = *(const bf16x8*)(lds + (PAR) * 32768 + aBase + ((FMB) + i) * 2048 + koff[kh]); }
  #define RD_B(D, PAR, FCB)                                                        \
    { _Pragma("unroll") for (int i = 0; i < 2; ++i)                                \
      _Pragma("unroll") for (int kh = 0; kh < 2; ++kh)                             \
        D[i][kh] = *(const bf16x8*)(lds + (PAR) * 32768 + bBase + ((FCB) + i) * 2048 + koff[kh]); }

  #define MM(B2, FMB, FCB)                                                         \
    { __builtin_amdgcn_s_setprio(1);                                               \
      _Pragma("unroll") for (int kh = 0; kh < 2; ++kh)                             \
      _Pragma("unroll") for (int i = 0; i < 4; ++i)                                \
      _Pragma("unroll") for (int j2 = 0; j2 < 2; ++j2)                             \
        acc[(FMB) + i][(FCB) + j2] = __builtin_amdgcn_mfma_f32_16x16x32_bf16(      \
            a[i][kh], B2[j2][kh], acc[(FMB) + i][(FCB) + j2], 0, 0, 0);            \
      __builtin_amdgcn_s_setprio(0); }

  // FENCED barrier: s_barrier alone is not a compiler fence (fix #1).
  #define BAR { __builtin_amdgcn_s_barrier(); __builtin_amdgcn_sched_barrier(0); }
  #define LGKM0 { asm volatile("s_waitcnt lgkmcnt(0)" ::: "memory"); __builtin_amdgcn_sched_barrier(0); }
  #define VM(N) { asm volatile("s_waitcnt vmcnt(" #N ")" ::: "memory"); __builtin_amdgcn_sched_barrier(0); }

  // ---- prologue: stage kt0 fully + kt1 {B0,B1,A0} (6 loads stay in flight) ----
  ST_B(0, 0); ST_B(0, 1); ST_A(0, 0); ST_A(0, 1);
  ST_B(1, 0); ST_B(1, 1); ST_A(1, 0);
  VM(6); BAR;

  #pragma unroll
  for (int t = 0; t < 4; ++t) {
    const int k1 = 2 * t + 1, k2 = 2 * t + 2, k3 = 2 * t + 3;
    // ---- kt = 2t (buf parity 0) ----
    // p0: ST_A(k1,1) writes parity 1 (opposite) -> safe anywhere.
    RD_A(0, 0); RD_B(b0, 0, 0);
    ST_A(k1, 1);
    BAR; LGKM0; MM(b0, 0, 0); BAR;
    // p1: no stage (same-parity B must wait until p2 -- fix #2).
    RD_B(b1, 0, 2);
    BAR; LGKM0; MM(b1, 0, 2); BAR;
    // p2: B buf0 fully sampled by all waves (p1 final BAR) -> ST_B(k2,0) safe.
    RD_A(0, 4);
    if (t < 3) ST_B(k2, 0);
    BAR; LGKM0; MM(b1, 4, 2); BAR;
    // p3: A buf0 fully sampled (p2 final BAR) -> ST_A(k2,0) safe; + ST_B(k2,1).
    if (t < 3) { ST_B(k2, 1); ST_A(k2, 0); }
    BAR; MM(b0, 4, 0);
    // gate kt=2t+1: outstanding = 6(kt1 rem) +2(p0) +2(p2) +4(p3) = 14 -> VM(6)
    // retires exactly kt(2t+1)'s 8. t=3: 8 outstanding -> VM(0).
    if (t < 3) { VM(6); } else { VM(0); }
    BAR;
    // ---- kt = 2t+1 (buf parity 1) ----
    // p4: ST_A(k2,1) writes parity 0; A buf0 sampled through p2 -> safe.
    RD_A(1, 0); RD_B(b0, 1, 0);
    if (t < 3) ST_A(k2, 1);
    BAR; LGKM0; MM(b0, 0, 0); BAR;
    // p5: no stage (same-parity B waits for p5 final BAR).
    RD_B(b1, 1, 2);
    BAR; LGKM0; MM(b1, 0, 2); BAR;
    // p6: B buf1 fully sampled -> both ST_B(k3,*) safe.
    RD_A(1, 4);
    if (t < 3) { ST_B(k3, 0); ST_B(k3, 1); }
    BAR; LGKM0; MM(b1, 4, 2); BAR;
    // p7: A buf1 fully sampled -> ST_A(k3,0) safe.
    if (t < 3) ST_A(k3, 0);
    BAR; MM(b0, 4, 0);
    // gate kt=2t+2: outstanding = 6 +2(p4) +4(p6) +2(p7) = 14 -> VM(6).
    if (t < 3) { VM(6); }
    BAR;
  }
  #undef ST_A
  #undef ST_B
  #undef RD_A
  #undef RD_B
  #undef MM
  #undef VM
  #undef LGKM0
  #undef BAR

  // ---- epilogue: i,o,u,f = acc[fm][0..3] in the SAME lane ----
  const int hcol = g * 64 + wn * 16 + l15;
  float b4[4];
  #pragma unroll
  for (int fc = 0; fc < 4; ++fc) b4[fc] = Bias[fc * 256 + hcol];
  #pragma unroll
  for (int fm = 0; fm < 8; ++fm) {
    #pragma unroll
    for (int reg = 0; reg < 4; ++reg) {
      int rowl = wm * 128 + fm * 16 + lhi * 4 + reg;  // 16x16 C/D map (m89/m91)
      size_t n = (size_t)(n0 + rowl);
      float i_ = acc[fm][0][reg] + b4[0];
      float o_ = acc[fm][1][reg] + b4[1];
      float u_ = acc[fm][2][reg] + b4[2];
      float fp = acc[fm][3][reg] + b4[3];
      float ccv = child_c[(size_t)lds_cidx[rowl] * 256 + hcol];
      float sigi = 1.f / (1.f + __expf(-i_));
      float sigo = 1.f / (1.f + __expf(-o_));
      float sigf = 1.f / (1.f + __expf(-fp));
      float tu = 2.f / (1.f + __expf(-2.f * u_)) - 1.f;
      float c = sigi * tu + sigf * ccv;
      float tc = 2.f / (1.f + __expf(-2.f * c)) - 1.f;
      out[n * 256 + hcol] = sigo * tc;
      out[NHOFF + n * 256 + hcol] = c;
    }
  }
}

// ---------- fallback main (round-1 proven path, used if ws too small) ----------
__global__ __launch_bounds__(256, 2)
void treelstm_main_f32(const float* __restrict__ x, const float* __restrict__ child_h,
                       const float* __restrict__ child_c, const int* __restrict__ cidx,
                       const u16* __restrict__ Bpack, const float* __restrict__ Bias,
                       float* __restrict__ out) {
  __shared__ __align__(16) u16 ldsA[128 * 64];
  __shared__ __align__(16) u16 ldsB[256 * 64];
  __shared__ int lds_cidx[128];

  const int tid = threadIdx.x;
  const int n0 = blockIdx.x * 128;
  const int g = blockIdx.y;

  if (tid < 128) lds_cidx[tid] = cidx[n0 + tid];

  const int lane = tid & 63, w = tid >> 6;
  const int wm = w >> 1, wn = w & 1;
  const int lr = lane & 31, hi = lane >> 5;

  f32x16 acc[2][4] = {};

  const char* ldsAb = (const char*)ldsA;
  const char* ldsBb = (const char*)ldsB;
  int arow[2];
  #pragma unroll
  for (int mi = 0; mi < 2; mi++) arow[mi] = (wm * 64 + mi * 32 + lr) * 128;
  const int aswz = (lr & 7) << 4;
  int brow[4];
  #pragma unroll
  for (int s = 0; s < 4; s++) brow[s] = (s * 64 + wn * 32 + lr) * 128;
  const int bswz = (lr & 7) << 4;

  for (int kt = 0; kt < 8; ++kt) {
    #pragma unroll
    for (int q = 0; q < 8; ++q) {
      int v = q * 256 + tid;
      int r = v >> 4;
      int kq = (v & 15) * 4;
      const float* src = (kt < 4) ? (x + (size_t)(n0 + r) * 256 + kt * 64 + kq)
                                  : (child_h + (size_t)lds_cidx[r] * 256 + (kt - 4) * 64 + kq);
      float4 d = *(const float4*)src;
      u16x4 b;
      b[0] = f2bf(d.x); b[1] = f2bf(d.y); b[2] = f2bf(d.z); b[3] = f2bf(d.w);
      int addr = (r * 128 + kq * 2) ^ ((r & 7) << 4);
      *(u16x4*)((char*)ldsA + addr) = b;
    }
    const u16* bsrc = Bpack + (g * 8 + kt) * 16384;
    #pragma unroll
    for (int q = 0; q < 8; ++q) {
      int m = q * 256 + tid;
      *(u16x8*)((char*)ldsB + m * 16) = *(const u16x8*)(bsrc + m * 8);
    }
    __syncthreads();
    #pragma unroll
    for (int ks = 0; ks < 4; ++ks) {
      int kb = ks * 32 + hi * 16;
      bf16x8 af[2], bfr[4];
      #pragma unroll
      for (int mi = 0; mi < 2; mi++)
        af[mi] = *(const bf16x8*)(ldsAb + ((arow[mi] + kb) ^ aswz));
      #pragma unroll
      for (int s = 0; s < 4; s++)
        bfr[s] = *(const bf16x8*)(ldsBb + ((brow[s] + kb) ^ bswz));
      #pragma unroll
      for (int mi = 0; mi < 2; mi++)
        #pragma unroll
        for (int s = 0; s < 4; s++)
          acc[mi][s] = __builtin_amdgcn_mfma_f32_32x32x16_bf16(af[mi], bfr[s], acc[mi][s], 0, 0, 0);
    }
    __syncthreads();
  }

  const int tcol = g * 64 + wn * 32 + lr;
  const float bi = Bias[tcol], bo = Bias[256 + tcol], bu = Bias[512 + tcol], bfg = Bias[768 + tcol];
  #pragma unroll
  for (int mi = 0; mi < 2; mi++) {
    #pragma unroll
    for (int reg = 0; reg < 16; ++reg) {
      int row = wm * 64 + mi * 32 + (reg & 3) + 8 * (reg >> 2) + 4 * hi;
      int n = n0 + row;
      float i_ = acc[mi][0][reg] + bi;
      float o_ = acc[mi][1][reg] + bo;
      float u_ = acc[mi][2][reg] + bu;
      float fp = acc[mi][3][reg] + bfg;
      float ccv = child_c[(size_t)lds_cidx[row] * 256 + tcol];
      float sigi = 1.f / (1.f + __expf(-i_));
      float sigo = 1.f / (1.f + __expf(-o_));
      float sigf = 1.f / (1.f + __expf(-fp));
      float tu = 2.f / (1.f + __expf(-2.f * u_)) - 1.f;
      float c = sigi * tu + sigf * ccv;
      float tc = 2.f / (1.f + __expf(-2.f * c)) - 1.f;
      out[(size_t)n * 256 + tcol] = sigo * tc;
      out[NHOFF + (size_t)n * 256 + tcol] = c;
    }
  }
}

extern "C" void kernel_launch(void* const* d_in, const int* in_sizes, int n_in,
                              void* d_out, int out_size, void* d_ws, size_t ws_size,
                              hipStream_t stream) {
  const float* x    = (const float*)d_in[0];
  const float* ch   = (const float*)d_in[1];
  const float* cc   = (const float*)d_in[2];
  const int*   ci   = (const int*)d_in[3];
  const float* Wiou = (const float*)d_in[4];
  const float* Uiou = (const float*)d_in[5];
  const float* biou = (const float*)d_in[6];
  const float* Wf   = (const float*)d_in[7];
  const float* Wfb  = (const float*)d_in[8];
  const float* Uf   = (const float*)d_in[9];
  const float* Ufb  = (const float*)d_in[10];
  const float* bfv  = (const float*)d_in[11];

  u16* Bpack = (u16*)d_ws;                              // 1 MB bf16 packed weights
  float* Bias = (float*)((char*)d_ws + (1 << 20));      // 4 KB combined bias
  u16* Apack = (u16*)((char*)d_ws + (2 << 20));         // 134.2 MB packed [x|hc] bf16

  const size_t need = (size_t)(2 << 20) + (size_t)NTOT * 512 * sizeof(u16);

  prep_bias<<<4, 256, 0, stream>>>(biou, Wfb, Ufb, bfv, Bias);

  if (ws_size >= need) {
    prep_w_v9<<<256, 256, 0, stream>>>(Wiou, Uiou, Wf, Uf, Bpack);
    prep_apack<<<32768, 256, 0, stream>>>(x, ch, ci, Apack);
    treelstm_v10<<<2048, 512, 0, stream>>>(Apack, Bpack, Bias, cc, ci, (float*)d_out);
  } else {
    prep_w_legacy<<<256, 256, 0, stream>>>(Wiou, Uiou, Wf, Uf, Bpack);
    dim3 grid(1024, 4);
    treelstm_main_f32<<<grid, 256, 0, stream>>>(x, ch, cc, ci, Bpack, Bias, (float*)d_out);
  }
}